// Round 7
// baseline (433.541 us; speedup 1.0000x reference)
//
#include <hip/hip_runtime.h>

#define N_TOK   16384
#define K_CODES 8192
#define DIMS    256
#define MARGIN  0.25f

// d_out offsets (floats): out, loss, idx, new_cluster_size, new_ema_w, new_embedding
#define OUT_OFF  0
#define LOSS_OFF 4194304
#define IDX_OFF  4194305
#define NCS_OFF  4210689
#define NEMA_OFF 4218881
#define NEMB_OFF 6316033

// ws byte offsets
#define WS_ZFRAG  0u          // ushort frag-order [512 tg][2 lv][16 ks][64 lane][8] = 16 MB
#define WS_EFRAG  16777216u   // ushort frag-order [256 g][2 lv][16 ks][64 lane][8] = 8 MB
#define WS_ENORM  25165824u   // f32 [8192]
#define WS_CNT    25198592u   // int [8192]
#define WS_CS     25231360u   // f32 [8192]
#define WS_OFFS   25264128u   // int [8192]
#define WS_WPOS   25296896u   // int [8192]
#define WS_TLIST  25329664u   // int [16384]
#define WS_IDXI   25395200u   // int [16384]
#define WS_GCNT   25460736u   // int [16384]
#define WS_DENOM  25526272u   // double
#define WS_GCAND  25526784u   // ushort [16384][64] = 2 MB

typedef _Float16 f16x8 __attribute__((ext_vector_type(8)));
typedef float    f32x16 __attribute__((ext_vector_type(16)));

union HU { _Float16 h; unsigned short u; };

static __device__ inline void split_f32(float x, unsigned short& hi, unsigned short& lo) {
    HU a; a.h = (_Float16)x;                    // RNE f32->f16
    float r = (x - (float)a.h) * 2048.0f;       // exact residual, scaled to normal range
    HU b; b.h = (_Float16)r;
    hi = a.u; lo = b.u;
}

static __device__ inline float join_f16(unsigned short h, unsigned short l) {
    HU a, b; a.u = h; b.u = l;
    return (float)a.h + (float)b.h * 4.8828125e-4f;
}

// async global->LDS, 16B per lane; LDS dest = wave-uniform base + lane*16
#define GLD16(gp, lp) __builtin_amdgcn_global_load_lds( \
    (const __attribute__((address_space(1))) unsigned int*)(gp), \
    (__attribute__((address_space(3))) unsigned int*)(lp), 16, 0, 0)

// ---- z [16][256][1024] f32 -> zfrag (frag-order, 2-level split); zeroes loss/denom ----
__global__ __launch_bounds__(256) void cvt_z_kernel(const float* __restrict__ z,
                                                    unsigned short* __restrict__ zfrag,
                                                    float* __restrict__ loss_cell,
                                                    double* __restrict__ denom) {
    __shared__ float T[64][65];
    const int t = threadIdx.x;
    const int hg = blockIdx.x & 15, dg = (blockIdx.x >> 4) & 3, b = blockIdx.x >> 6;
    if (blockIdx.x == 0 && t == 0) { *loss_cell = 0.f; *denom = 0.0; }
    const int c4 = (t & 15) * 4, r0 = t >> 4;
    const float* zb = z + (((size_t)(b * 256 + dg * 64)) << 10) + hg * 64;
#pragma unroll
    for (int p = 0; p < 4; ++p) {
        const int r = r0 + p * 16;
        const float4 v = *(const float4*)(zb + ((size_t)r << 10) + c4);
        T[r][c4] = v.x; T[r][c4 + 1] = v.y; T[r][c4 + 2] = v.z; T[r][c4 + 3] = v.w;
    }
    __syncthreads();
    const int tr = t & 63, dc = (t >> 6) * 16;
    const int tile = b * 16 + hg;
    const int tg = tile * 2 + (tr >> 5), l31 = tr & 31;
    const int ks = dg * 4 + (dc >> 4);
    unsigned short hb[16], lb[16];
#pragma unroll
    for (int j = 0; j < 16; ++j) split_f32(T[dc + j][tr], hb[j], lb[j]);
#pragma unroll
    for (int lv = 0; lv < 2; ++lv) {
        const unsigned short* src = lv ? lb : hb;
        unsigned short* dst = zfrag + (size_t)((tg * 2 + lv) * 16 + ks) * 512;
        *(uint4*)(dst + l31 * 8)       = ((const uint4*)src)[0];   // khalf 0
        *(uint4*)(dst + 256 + l31 * 8) = ((const uint4*)src)[1];   // khalf 1
    }
}

// ---- emb -> efrag + ||e||^2 (f64) + zero cnt/gcnt. grid: 256 blocks ----
__global__ __launch_bounds__(256) void cvt_e_enorm(const float* __restrict__ emb,
                                                   unsigned short* __restrict__ efrag,
                                                   float* __restrict__ enorm,
                                                   int* __restrict__ cnt,
                                                   int* __restrict__ gcnt) {
    __shared__ double red[256];
    const int t = threadIdx.x, g = blockIdx.x;
    const int lane = t & 63, q = t >> 6;
    const int l31 = lane & 31, lhi = lane >> 5;
    if (g < 32) cnt[g * 256 + t] = 0;
    if (g < 64) gcnt[g * 256 + t] = 0;
    const float* rowp = emb + (size_t)(g * 32 + l31) * 256 + lhi * 8;
    double s = 0.0;
#pragma unroll
    for (int kk = 0; kk < 4; ++kk) {
        const int ks = q * 4 + kk;
        const float4 a = *(const float4*)(rowp + ks * 16);
        const float4 bq = *(const float4*)(rowp + ks * 16 + 4);
        const float vv[8] = {a.x, a.y, a.z, a.w, bq.x, bq.y, bq.z, bq.w};
        unsigned short hb[8], lb[8];
#pragma unroll
        for (int j = 0; j < 8; ++j) {
            split_f32(vv[j], hb[j], lb[j]);
            s += (double)vv[j] * (double)vv[j];
        }
        *(uint4*)(efrag + (size_t)((g * 2 + 0) * 16 + ks) * 512 + lane * 8) = *(const uint4*)hb;
        *(uint4*)(efrag + (size_t)((g * 2 + 1) * 16 + ks) * 512 + lane * 8) = *(const uint4*)lb;
    }
    red[t] = s;
    __syncthreads();
    if (t < 32) {
        double acc = 0.0;
#pragma unroll
        for (int qq = 0; qq < 4; ++qq) acc += red[qq * 64 + t] + red[qq * 64 + 32 + t];
        enorm[g * 32 + t] = (float)acc;
    }
}

// ---- pass 1: hi-only approx distances + candidate collection ----
// grid 512 = 128 token-tiles x 4 code-splits; 4 waves; Z-hi register-resident.
__global__ __launch_bounds__(256, 2) void argmin_approx(
    const unsigned short* __restrict__ zfrag, const unsigned short* __restrict__ efrag,
    const float* __restrict__ enorm, int* __restrict__ gcnt,
    unsigned short* __restrict__ gcand) {
    __shared__ __align__(16) unsigned short E[2][4096];  // [buf][(cg*4+ksl)*512 + lane*8]
    __shared__ float en_s[2][64];
    __shared__ unsigned short lcand[128][32];
    __shared__ int lcnt[128];

    const int tid = threadIdx.x, lane = tid & 63, wave = tid >> 6;
    const int tile = blockIdx.x >> 2, csplit = blockIdx.x & 3;
    const int token0 = tile * 128, code0 = csplit * 2048;

    if (tid < 128) lcnt[tid] = 0;

    // register-resident Z-hi frags for this wave's 32-token group
    f16x8 Zr[16];
    {
        const unsigned short* zb = zfrag + (size_t)(tile * 4 + wave) * 16384 + lane * 8;
#pragma unroll
        for (int ks = 0; ks < 16; ++ks) Zr[ks] = *(const f16x8*)(zb + ks * 512);
    }

    // prologue: chunk (ct=0,kc=0) -> buf0 (wave stages ksl=wave for both cg)
#pragma unroll
    for (int cg = 0; cg < 2; ++cg)
        GLD16(efrag + ((size_t)(csplit * 64 + cg) * 32 + wave) * 512 + lane * 8,
              &E[0][(cg * 4 + wave) * 512]);
    if (tid < 64) en_s[0][tid] = enorm[code0 + tid];
    __syncthreads();

    float bv = 3.4e38f;

    for (int ct = 0; ct < 32; ++ct) {
        f32x16 acc[2];
#pragma unroll
        for (int cg = 0; cg < 2; ++cg)
#pragma unroll
            for (int qq = 0; qq < 16; ++qq) acc[cg][qq] = 0.f;

#pragma unroll
        for (int kc = 0; kc < 4; ++kc) {
            const int p = (ct * 4 + kc) & 1;
            if (!(ct == 31 && kc == 3)) {
                const int nch = ct * 4 + kc + 1;
                const int nct = nch >> 2, nkc = nch & 3;
#pragma unroll
                for (int cg = 0; cg < 2; ++cg)
                    GLD16(efrag + ((size_t)(csplit * 64 + nct * 2 + cg) * 32 + nkc * 4 + wave) * 512 + lane * 8,
                          &E[p ^ 1][(cg * 4 + wave) * 512]);
            }
            if (kc == 0 && ct < 31 && tid < 64)
                en_s[(ct + 1) & 1][tid] = enorm[code0 + (ct + 1) * 64 + tid];

#pragma unroll
            for (int ksl = 0; ksl < 4; ++ksl) {
                const f16x8 ae0 = *(const f16x8*)&E[p][(0 * 4 + ksl) * 512 + lane * 8];
                const f16x8 ae1 = *(const f16x8*)&E[p][(1 * 4 + ksl) * 512 + lane * 8];
                acc[0] = __builtin_amdgcn_mfma_f32_32x32x16_f16(ae0, Zr[kc * 4 + ksl], acc[0], 0, 0, 0);
                acc[1] = __builtin_amdgcn_mfma_f32_32x32x16_f16(ae1, Zr[kc * 4 + ksl], acc[1], 0, 0, 0);
            }
            if (kc == 3) {
                // phase 1: s = ||e||^2 - 2*zh.eh (overwrite acc), update per-lane min
                const int rbase = 4 * (lane >> 5);
                const float* ens = en_s[ct & 1];
#pragma unroll
                for (int cg = 0; cg < 2; ++cg)
#pragma unroll
                    for (int r = 0; r < 16; ++r) {
                        const int cl = cg * 32 + (r & 3) + 8 * (r >> 2) + rbase;
                        const float sv = ens[cl] - 2.0f * acc[cg][r];
                        acc[cg][r] = sv;
                        if (sv < bv) bv = sv;
                    }
                // phase 2: pair-share min (incl. current chunk), collect candidates
                const float ob = __shfl_xor(bv, 32);
                const float thr = fminf(bv, ob) + MARGIN;
                const int tl = wave * 32 + (lane & 31);
#pragma unroll
                for (int cg = 0; cg < 2; ++cg)
#pragma unroll
                    for (int r = 0; r < 16; ++r)
                        if (acc[cg][r] < thr) {
                            const int cl = cg * 32 + (r & 3) + 8 * (r >> 2) + rbase;
                            const int code = code0 + ct * 64 + cl;
                            const int pp = atomicAdd(&lcnt[tl], 1);
                            if (pp < 32) lcand[tl][pp] = (unsigned short)code;
                            else {
                                const int gp = atomicAdd(&gcnt[token0 + tl], 1);
                                if (gp < 64) gcand[(size_t)(token0 + tl) * 64 + gp] = (unsigned short)code;
                            }
                        }
            }
            __syncthreads();
        }
    }
    // flush LDS lists to global
    if (lane < 32) {
        const int tl = wave * 32 + lane;
        const int token = token0 + tl;
        const int L = min(lcnt[tl], 32);
        const int base = atomicAdd(&gcnt[token], L);
        for (int i = 0; i < L; ++i) {
            const int gp = base + i;
            if (gp < 64) gcand[(size_t)token * 64 + gp] = lcand[tl][i];
        }
    }
}

// ---- pass 2: exact f32 rescore of candidates; emits idx + counts ----
// grid 4096 x 256: one wave per token
__global__ __launch_bounds__(256) void rescore_kernel(
    const unsigned short* __restrict__ zfrag, const unsigned short* __restrict__ efrag,
    const float* __restrict__ enorm, const int* __restrict__ gcnt,
    const unsigned short* __restrict__ gcand, int* __restrict__ idx_i,
    float* __restrict__ idx_f, int* __restrict__ cnt) {
    const int lane = threadIdx.x & 63, wave = threadIdx.x >> 6;
    const int t = blockIdx.x * 4 + wave;
    // lane covers dims lane*4 .. +3
    const int ks = lane >> 2, khalf = (lane >> 1) & 1, j0 = (lane & 1) * 4;
    const int loff = khalf * 256 + j0;
    const int tg = t >> 5, tl = t & 31;
    float zf[4];
    {
        const ushort4 hv = *(const ushort4*)(zfrag + (size_t)((tg * 2 + 0) * 16 + ks) * 512 + loff + tl * 8);
        const ushort4 lv = *(const ushort4*)(zfrag + (size_t)((tg * 2 + 1) * 16 + ks) * 512 + loff + tl * 8);
        const unsigned short* hp = (const unsigned short*)&hv;
        const unsigned short* lp = (const unsigned short*)&lv;
#pragma unroll
        for (int j = 0; j < 4; ++j) zf[j] = join_f16(hp[j], lp[j]);
    }
    const int C = min(gcnt[t], 64);
    float best = 3.4e38f; int besti = 0;
    for (int i = 0; i < C; ++i) {
        const int c = gcand[(size_t)t * 64 + i];
        const int g = c >> 5, cl = c & 31;
        const ushort4 he = *(const ushort4*)(efrag + (size_t)((g * 2 + 0) * 16 + ks) * 512 + loff + cl * 8);
        const ushort4 le = *(const ushort4*)(efrag + (size_t)((g * 2 + 1) * 16 + ks) * 512 + loff + cl * 8);
        const unsigned short* hp = (const unsigned short*)&he;
        const unsigned short* lp = (const unsigned short*)&le;
        float dot = 0.f;
#pragma unroll
        for (int j = 0; j < 4; ++j) dot += zf[j] * join_f16(hp[j], lp[j]);
#pragma unroll
        for (int off = 32; off; off >>= 1) dot += __shfl_xor(dot, off);
        const float s = enorm[c] - 2.0f * dot;
        if (s < best || (s == best && c < besti)) { best = s; besti = c; }
    }
    if (lane == 0) {
        idx_i[t] = besti;
        idx_f[t] = (float)besti;
        atomicAdd(&cnt[besti], 1);
    }
}

// ---- exclusive scan of 8192 counts (single block) ----
__global__ __launch_bounds__(256) void scan_kernel(const int* __restrict__ cnt,
                                                   int* __restrict__ offs,
                                                   int* __restrict__ wpos) {
    __shared__ int part[256];
    const int tid = threadIdx.x;
    const int base = tid * 32;
    int loc[32];
    int s = 0;
#pragma unroll
    for (int j = 0; j < 32; ++j) { loc[j] = cnt[base + j]; s += loc[j]; }
    part[tid] = s;
    __syncthreads();
    for (int off = 1; off < 256; off <<= 1) {
        int v = 0;
        if (tid >= off) v = part[tid - off];
        __syncthreads();
        if (tid >= off) part[tid] += v;
        __syncthreads();
    }
    int run = (tid > 0) ? part[tid - 1] : 0;
#pragma unroll
    for (int j = 0; j < 32; ++j) {
        offs[base + j] = run;
        wpos[base + j] = run;
        run += loc[j];
    }
}

// ---- fused: scatter token ids (blocks 0-63) + cs/denom (blocks 64-95) ----
__global__ __launch_bounds__(256) void scatter_cs(
    const int* __restrict__ idx_i, int* __restrict__ wpos, int* __restrict__ tlist,
    const float* __restrict__ cluster_size, const int* __restrict__ cnt,
    float* __restrict__ cs, double* __restrict__ denom) {
    __shared__ double red[256];
    const int t = threadIdx.x, b = blockIdx.x;
    if (b < 64) {
        const int n = b * 256 + t;
        const int k = idx_i[n];
        tlist[atomicAdd(&wpos[k], 1)] = n;
    } else {
        const int k = (b - 64) * 256 + t;
        const float v = cluster_size[k] * 0.99f + 0.01f * (float)cnt[k] + 1e-5f;
        cs[k] = v;
        red[t] = (double)v;
        __syncthreads();
        for (int s2 = 128; s2; s2 >>= 1) {
            if (t < s2) red[t] += red[t + s2];
            __syncthreads();
        }
        if (t == 0) atomicAdd(denom, red[0]);
    }
}

// ---- fused: nema_finalize (blocks 0-2047, 4 codes each) + gather/loss (2048-3071) ----
__global__ __launch_bounds__(256) void nema_gather(
    const unsigned short* __restrict__ zfrag,
    const int* __restrict__ offs, const int* __restrict__ cnt, const int* __restrict__ tlist,
    const float* __restrict__ ema_w, const float* __restrict__ cs,
    const double* __restrict__ denom, float* __restrict__ ncs_out,
    float* __restrict__ nema_out, float* __restrict__ nemb_out,
    const float* __restrict__ z, const float* __restrict__ emb,
    const int* __restrict__ idx_i, float* __restrict__ out, float* __restrict__ loss_cell) {
    __shared__ float redf[256];
    const int t = threadIdx.x;
    if (blockIdx.x < 2048) {
        const int lane = t & 63, wave = t >> 6;
        const int k = blockIdx.x * 4 + wave;
        const int l31 = lane & 31, sel = lane >> 5;
        const int beg = offs[k], c = cnt[k];
        float acc[8] = {0.f, 0.f, 0.f, 0.f, 0.f, 0.f, 0.f, 0.f};
        for (int i = 0; i < c; ++i) {
            const int tok = tlist[beg + i];
            const int tg = tok >> 5, tl = tok & 31;
            const uint4 v = *(const uint4*)(zfrag +
                (size_t)((tg * 2 + sel) * 16 + (l31 >> 1)) * 512 + (l31 & 1) * 256 + tl * 8);
            uint4 o;
            o.x = __shfl_xor((int)v.x, 32); o.y = __shfl_xor((int)v.y, 32);
            o.z = __shfl_xor((int)v.z, 32); o.w = __shfl_xor((int)v.w, 32);
            if (lane < 32) {
                const unsigned short* hp = (const unsigned short*)&v;
                const unsigned short* lp = (const unsigned short*)&o;
#pragma unroll
                for (int j = 0; j < 8; ++j) acc[j] += join_f16(hp[j], lp[j]);
            }
        }
        const float dn = (float)(*denom) + (float)K_CODES * 1e-5f;
        const float ncs = cs[k] / dn;
        if (lane == 0) ncs_out[k] = ncs;
        if (lane < 32) {
            const size_t off = ((size_t)k << 8) + l31 * 8;
#pragma unroll
            for (int j = 0; j < 8; ++j) {
                const float ne = ema_w[off + j] * 0.99f + 0.01f * acc[j];
                nema_out[off + j] = ne;
                nemb_out[off + j] = ne / ncs;
            }
        }
    } else {
        const int gb = blockIdx.x - 2048;
        const int n0 = (gb >> 2) * 64;
        const int dg = (gb & 3) * 64;
        const int b = n0 >> 10, hw0 = n0 & 1023;
        const int lane = t & 63, w = t >> 6;
        const int n = n0 + lane;
        const int k = idx_i[n];
        const float* zb = z + ((size_t)b << 18) + hw0 + lane;
        float* ob = out + ((size_t)b << 18) + hw0 + lane;
        float ls = 0.f;
#pragma unroll 4
        for (int d = dg + w; d < dg + 64; d += 4) {
            const float zv = zb[(size_t)d << 10];
            const float ev = emb[((size_t)k << 8) + d];
            ob[(size_t)d << 10] = ev;
            const float df = ev - zv;
            ls += df * df;
        }
        redf[t] = ls;
        __syncthreads();
        for (int s2 = 128; s2; s2 >>= 1) {
            if (t < s2) redf[t] += redf[t + s2];
            __syncthreads();
        }
        if (t == 0) atomicAdd(loss_cell, redf[0] * (0.25f / 4194304.0f));
    }
}

// ---------------- launch ----------------
extern "C" void kernel_launch(void* const* d_in, const int* in_sizes, int n_in,
                              void* d_out, int out_size, void* d_ws, size_t ws_size,
                              hipStream_t stream) {
    const float* z            = (const float*)d_in[0];
    const float* emb          = (const float*)d_in[1];
    const float* cluster_size = (const float*)d_in[2];
    const float* ema_w        = (const float*)d_in[3];
    float* out = (float*)d_out;
    char*  wsb = (char*)d_ws;

    unsigned short* zfrag = (unsigned short*)(wsb + WS_ZFRAG);
    unsigned short* efrag = (unsigned short*)(wsb + WS_EFRAG);
    float*  enorm  = (float*)(wsb + WS_ENORM);
    int*    cnt    = (int*)(wsb + WS_CNT);
    float*  cs     = (float*)(wsb + WS_CS);
    int*    offs   = (int*)(wsb + WS_OFFS);
    int*    wpos   = (int*)(wsb + WS_WPOS);
    int*    tlist  = (int*)(wsb + WS_TLIST);
    int*    idx_i  = (int*)(wsb + WS_IDXI);
    int*    gcnt   = (int*)(wsb + WS_GCNT);
    double* denom  = (double*)(wsb + WS_DENOM);
    unsigned short* gcand = (unsigned short*)(wsb + WS_GCAND);

    cvt_z_kernel<<<1024, 256, 0, stream>>>(z, zfrag, out + LOSS_OFF, denom);
    cvt_e_enorm<<<256, 256, 0, stream>>>(emb, efrag, enorm, cnt, gcnt);
    argmin_approx<<<512, 256, 0, stream>>>(zfrag, efrag, enorm, gcnt, gcand);
    rescore_kernel<<<4096, 256, 0, stream>>>(zfrag, efrag, enorm, gcnt, gcand,
                                             idx_i, out + IDX_OFF, cnt);
    scan_kernel<<<1, 256, 0, stream>>>(cnt, offs, wpos);
    scatter_cs<<<96, 256, 0, stream>>>(idx_i, wpos, tlist, cluster_size, cnt, cs, denom);
    nema_gather<<<3072, 256, 0, stream>>>(zfrag, offs, cnt, tlist, ema_w, cs, denom,
                                          out + NCS_OFF, out + NEMA_OFF, out + NEMB_OFF,
                                          z, emb, idx_i, out + OUT_OFF, out + LOSS_OFF);
}